// Round 5
// baseline (574.632 us; speedup 1.0000x reference)
//
#include <hip/hip_runtime.h>

#define NN 100000
#define NE 1600000
#define D1 128
#define D2 64
#define BN_EPS 1e-5f
#define SCAN_CHUNK 512
#define NB_SCAN ((NN + SCAN_CHUNK - 1) / SCAN_CHUNK)   // 196

typedef unsigned int uint32;
typedef unsigned long long u64;
typedef float __attribute__((ext_vector_type(4))) f32x4;

// ---- bf16 helpers (RNE) ----
__device__ __forceinline__ uint32 f2bf_pair(float a, float b) {
    uint32 ua = __float_as_uint(a), ub = __float_as_uint(b);
    ua = (ua + 0x7FFFu + ((ua >> 16) & 1u)) >> 16;
    ub = (ub + 0x7FFFu + ((ub >> 16) & 1u)) >> 16;
    return ua | (ub << 16);
}
__device__ __forceinline__ float bf_lo(uint32 v) { return __uint_as_float(v << 16); }
__device__ __forceinline__ float bf_hi(uint32 v) { return __uint_as_float(v & 0xFFFF0000u); }

__device__ __forceinline__ float4 nt_load4(const float* p) {
    f32x4 v = __builtin_nontemporal_load((const f32x4*)p);
    return make_float4(v.x, v.y, v.z, v.w);
}

// ---------------- degree count (int atomics, from dst) ----------------
__global__ __launch_bounds__(256) void cnt_k(const int* __restrict__ dst,
                                             int* __restrict__ cnt) {
    int i = blockIdx.x * 256 + threadIdx.x;
    if (i < NE) atomicAdd(&cnt[dst[i]], 1);
}

// ---------------- dis = rsqrt(cnt+1) ----------------
__global__ __launch_bounds__(256) void make_dis_k(const int* __restrict__ cnt,
                                                  float* __restrict__ dis) {
    int i = blockIdx.x * 256 + threadIdx.x;
    if (i < NN) dis[i] = rsqrtf((float)cnt[i] + 1.0f);
}

// ---------------- prefix scan (3 kernels) ----------------
__global__ __launch_bounds__(SCAN_CHUNK) void scan1_k(const int* __restrict__ cnt,
                                                      int* __restrict__ rowptr,
                                                      int* __restrict__ bsum) {
    __shared__ int sh[SCAN_CHUNK];
    int tid = threadIdx.x;
    int g = blockIdx.x * SCAN_CHUNK + tid;
    int v = (g < NN) ? cnt[g] : 0;
    sh[tid] = v;
    __syncthreads();
    for (int o = 1; o < SCAN_CHUNK; o <<= 1) {
        int t = (tid >= o) ? sh[tid - o] : 0;
        __syncthreads();
        sh[tid] += t;
        __syncthreads();
    }
    if (g < NN) rowptr[g] = sh[tid] - v;
    if (tid == SCAN_CHUNK - 1) bsum[blockIdx.x] = sh[tid];
}

__global__ void scan2_k(int* __restrict__ bsum) {
    if (threadIdx.x == 0 && blockIdx.x == 0) {
        int a = 0;
        for (int i = 0; i < NB_SCAN; ++i) { int t = bsum[i]; bsum[i] = a; a += t; }
    }
}

__global__ __launch_bounds__(256) void scan3_k(int* __restrict__ rowptr,
                                               const int* __restrict__ bsum) {
    int g = blockIdx.x * 256 + threadIdx.x;
    if (g < NN) rowptr[g] += bsum[g >> 9];
    if (g == 0) rowptr[NN] = NE;
}

// ---------------- CSR fill: slot-atomic per edge; pack (src, weight) in 8B ----------------
__global__ __launch_bounds__(256) void fill_k(const int* __restrict__ src,
                                              const int* __restrict__ dst,
                                              const int* __restrict__ rowptr,
                                              const float* __restrict__ dis,
                                              int* __restrict__ cur,
                                              u64* __restrict__ edges) {
    int e = blockIdx.x * 256 + threadIdx.x;
    if (e >= NE) return;
    int d = dst[e];
    int s = src[e];
    int p = rowptr[d] + atomicAdd(&cur[d], 1);
    u64 pk = ((u64)__float_as_uint(dis[s] * dis[d]) << 32) | (uint32)s;
    edges[p] = pk;
}

// ---------------- BN coefficients ----------------
__global__ void bncoef_k(const float* __restrict__ sums, const float* __restrict__ ssq,
                         const float* __restrict__ g, const float* __restrict__ beta,
                         float* __restrict__ coef, int dim) {
    int c = threadIdx.x;
    if (c >= dim) return;
    float m = sums[c] * (1.0f / NN);
    float var = ssq[c] * (1.0f / NN) - m * m;
    float sc = g[c] * rsqrtf(var + BN_EPS);
    coef[c] = sc;
    coef[dim + c] = beta[c] - m * sc;
}

// ---------------- GEMM: Y[NN,OUT](bf16) = f(X)[NN,128] @ W[128,OUT] ----------------
template<int OUT, bool FUSE_BN>
__global__ __launch_bounds__(256, 3) void gemm_k(const float* __restrict__ X,
                                                 const float* __restrict__ W,
                                                 const float* __restrict__ coef,
                                                 uint32* __restrict__ Yb) {
    constexpr int CG = OUT / 4;      // col groups (32 or 16)
    constexpr int RG = 256 / CG;     // row groups (8 or 16)
    constexpr int R  = 64 / RG;      // rows/thread (8 or 4)
    __shared__ float sW[32 * OUT];
    __shared__ float sc[128], sh[128];
    if constexpr (FUSE_BN) {
        if (threadIdx.x < 128) {
            sc[threadIdx.x] = coef[threadIdx.x];
            sh[threadIdx.x] = coef[128 + threadIdx.x];
        }
    }
    const int cg = threadIdx.x % CG;
    const int rg = threadIdx.x / CG;
    const int row0 = blockIdx.x * 64 + rg * R;
    int rows[R];
    #pragma unroll
    for (int r = 0; r < R; ++r) rows[r] = min(row0 + r, NN - 1);
    float acc[R][4];
    #pragma unroll
    for (int r = 0; r < R; ++r)
        acc[r][0] = acc[r][1] = acc[r][2] = acc[r][3] = 0.f;

    for (int kc = 0; kc < 128; kc += 32) {
        for (int i = threadIdx.x; i < 32 * OUT / 4; i += 256)
            ((float4*)sW)[i] = ((const float4*)(W + (size_t)kc * OUT))[i];
        __syncthreads();
        #pragma unroll 2
        for (int k = 0; k < 32; k += 4) {
            float4 xv[R];
            #pragma unroll
            for (int r = 0; r < R; ++r) {
                xv[r] = nt_load4(X + (size_t)rows[r] * 128 + kc + k);
                if constexpr (FUSE_BN) {
                    float4 s4 = *(const float4*)&sc[kc + k];
                    float4 h4 = *(const float4*)&sh[kc + k];
                    xv[r].x = fmaxf(fmaf(xv[r].x, s4.x, h4.x), 0.f);
                    xv[r].y = fmaxf(fmaf(xv[r].y, s4.y, h4.y), 0.f);
                    xv[r].z = fmaxf(fmaf(xv[r].z, s4.z, h4.z), 0.f);
                    xv[r].w = fmaxf(fmaf(xv[r].w, s4.w, h4.w), 0.f);
                }
            }
            #pragma unroll
            for (int kk = 0; kk < 4; ++kk) {
                float4 w = *(const float4*)&sW[(k + kk) * OUT + cg * 4];
                #pragma unroll
                for (int r = 0; r < R; ++r) {
                    float xs = ((const float*)&xv[r])[kk];
                    acc[r][0] = fmaf(xs, w.x, acc[r][0]);
                    acc[r][1] = fmaf(xs, w.y, acc[r][1]);
                    acc[r][2] = fmaf(xs, w.z, acc[r][2]);
                    acc[r][3] = fmaf(xs, w.w, acc[r][3]);
                }
            }
        }
        __syncthreads();
    }
    // keep cacheable: next kernel gathers from Yb
    #pragma unroll
    for (int r = 0; r < R; ++r)
        if (row0 + r < NN) {
            uint32 p0 = f2bf_pair(acc[r][0], acc[r][1]);
            uint32 p1 = f2bf_pair(acc[r][2], acc[r][3]);
            *(uint2*)&Yb[(size_t)(row0 + r) * (OUT / 2) + cg * 2] = make_uint2(p0, p1);
        }
}

// ---------------- fused: CSR gather-aggregate (bf16 xw) + self-loop + bias + BN stats ----------------
template<int DIM>
__global__ __launch_bounds__(256) void agg_k(const int* __restrict__ rowptr,
                                             const u64* __restrict__ edges,
                                             const float* __restrict__ dis,
                                             const uint32* __restrict__ xwb,  // bf16 pairs
                                             const float* __restrict__ b,
                                             float* __restrict__ agg,
                                             float* __restrict__ sums,
                                             float* __restrict__ ssq) {
    const int lane = threadIdx.x & 63;
    const int wid = (blockIdx.x * 256 + threadIdx.x) >> 6;
    const int nwaves = gridDim.x * 4;
    float s0 = 0.f, s1 = 0.f, q0 = 0.f, q1 = 0.f;

    if constexpr (DIM == 128) {
        const float bc0 = b[lane * 2], bc1 = b[lane * 2 + 1];
        for (int n = wid; n < NN; n += nwaves) {
            const int beg = rowptr[n], end = rowptr[n + 1];
            const float dn = dis[n];
            float ax = 0.f, ay = 0.f;
            int e = beg;
            for (; e + 8 <= end; e += 8) {
                // one lane-replicated 8B nt load covers 8 edges; shfl-broadcast
                u64 ed = __builtin_nontemporal_load(&edges[e + (lane & 7)]);
                uint32 vv[8]; float ww[8];
                #pragma unroll
                for (int j = 0; j < 8; ++j) {
                    int s = __shfl((int)(uint32)ed, j);
                    ww[j] = __uint_as_float((uint32)__shfl((int)(uint32)(ed >> 32), j));
                    vv[j] = xwb[(size_t)s * 64 + lane];
                }
                #pragma unroll
                for (int j = 0; j < 8; ++j) {
                    ax = fmaf(bf_lo(vv[j]), ww[j], ax);
                    ay = fmaf(bf_hi(vv[j]), ww[j], ay);
                }
            }
            for (; e < end; ++e) {
                u64 ed = edges[e];
                float w = __uint_as_float((uint32)(ed >> 32));
                uint32 v = xwb[(size_t)(uint32)ed * 64 + lane];
                ax = fmaf(bf_lo(v), w, ax);
                ay = fmaf(bf_hi(v), w, ay);
            }
            float sl = dn * dn;  // 1/(deg+1) self-loop norm
            uint32 xv = xwb[(size_t)n * 64 + lane];
            ax = fmaf(bf_lo(xv), sl, ax) + bc0;
            ay = fmaf(bf_hi(xv), sl, ay) + bc1;
            u64 o = ((u64)__float_as_uint(ay) << 32) | __float_as_uint(ax);
            __builtin_nontemporal_store(o, (u64*)&agg[(size_t)n * 128 + lane * 2]);
            s0 += ax; q0 = fmaf(ax, ax, q0);
            s1 += ay; q1 = fmaf(ay, ay, q1);
        }
    } else {
        const unsigned short* xws = (const unsigned short*)xwb;
        const float bc0 = b[lane];
        for (int n = wid; n < NN; n += nwaves) {
            const int beg = rowptr[n], end = rowptr[n + 1];
            const float dn = dis[n];
            float ax = 0.f;
            int e = beg;
            for (; e + 8 <= end; e += 8) {
                u64 ed = __builtin_nontemporal_load(&edges[e + (lane & 7)]);
                uint32 vv[8]; float ww[8];
                #pragma unroll
                for (int j = 0; j < 8; ++j) {
                    int s = __shfl((int)(uint32)ed, j);
                    ww[j] = __uint_as_float((uint32)__shfl((int)(uint32)(ed >> 32), j));
                    vv[j] = (uint32)xws[(size_t)s * 64 + lane];
                }
                #pragma unroll
                for (int j = 0; j < 8; ++j)
                    ax = fmaf(__uint_as_float(vv[j] << 16), ww[j], ax);
            }
            for (; e < end; ++e) {
                u64 ed = edges[e];
                float w = __uint_as_float((uint32)(ed >> 32));
                ax = fmaf(__uint_as_float((uint32)xws[(size_t)(uint32)ed * 64 + lane] << 16),
                          w, ax);
            }
            ax = fmaf(__uint_as_float((uint32)xws[(size_t)n * 64 + lane] << 16),
                      dn * dn, ax) + bc0;
            __builtin_nontemporal_store(ax, &agg[(size_t)n * 64 + lane]);
            s0 += ax; q0 = fmaf(ax, ax, q0);
        }
    }

    __shared__ float ls[2 * DIM];
    if (threadIdx.x < 2 * DIM) ls[threadIdx.x] = 0.f;
    __syncthreads();
    if constexpr (DIM == 128) {
        atomicAdd(&ls[lane * 2], s0);
        atomicAdd(&ls[lane * 2 + 1], s1);
        atomicAdd(&ls[DIM + lane * 2], q0);
        atomicAdd(&ls[DIM + lane * 2 + 1], q1);
    } else {
        atomicAdd(&ls[lane], s0);
        atomicAdd(&ls[DIM + lane], q0);
    }
    __syncthreads();
    if (threadIdx.x < DIM) atomicAdd(&sums[threadIdx.x], ls[threadIdx.x]);
    else if (threadIdx.x < 2 * DIM) atomicAdd(&ssq[threadIdx.x - DIM], ls[threadIdx.x]);
}

// ---------------- final: out = relu(BN2(h2)) @ Wf + bf ----------------
__global__ __launch_bounds__(256) void final_k(const float* __restrict__ h,
                                               const float* __restrict__ coef,
                                               const float* __restrict__ Wf,
                                               const float* __restrict__ bf,
                                               float* __restrict__ out) {
    int wid = (blockIdx.x * 256 + threadIdx.x) >> 6;
    int lane = threadIdx.x & 63;
    if (wid >= NN) return;
    float v = fmaxf(fmaf(h[(size_t)wid * 64 + lane], coef[lane], coef[64 + lane]), 0.f)
              * Wf[lane];
    #pragma unroll
    for (int o = 32; o > 0; o >>= 1) v += __shfl_down(v, o);
    if (lane == 0) out[wid] = v + bf[0];
}

extern "C" void kernel_launch(void* const* d_in, const int* in_sizes, int n_in,
                              void* d_out, int out_size, void* d_ws, size_t ws_size,
                              hipStream_t stream) {
    const float* x   = (const float*)d_in[0];
    const int*   ei  = (const int*)d_in[1];
    const int*   src = ei;
    const int*   dst = ei + NE;
    const float* W1  = (const float*)d_in[2];
    const float* b1  = (const float*)d_in[3];
    const float* g1  = (const float*)d_in[4];
    const float* be1 = (const float*)d_in[5];
    const float* W2  = (const float*)d_in[6];
    const float* b2  = (const float*)d_in[7];
    const float* g2  = (const float*)d_in[8];
    const float* be2 = (const float*)d_in[9];
    const float* Wf  = (const float*)d_in[10];
    const float* bf  = (const float*)d_in[11];
    float* out = (float*)d_out;

    // ---- workspace layout ----
    uint32* xwb  = (uint32*)d_ws;                      // NN*64 uint32 (bf16 pairs, 25.6MB)
    float* agg1  = (float*)(xwb + (size_t)NN * 64);    // NN*128 f32
    float* agg2  = agg1  + (size_t)NN * D1;            // NN*64 f32
    float* dis   = agg2  + (size_t)NN * D2;            // NN
    float* sums1 = dis   + NN;                         // 128
    float* ssq1  = sums1 + D1;
    float* sums2 = ssq1  + D1;
    float* ssq2  = sums2 + D2;
    float* coef1 = ssq2  + D2;                         // 256
    float* coef2 = coef1 + 2 * D1;                     // 128
    int*   cnt    = (int*)(coef2 + 2 * D2);            // NN
    int*   cur    = cnt + NN;                          // NN
    int*   rowptr = cur + NN;                          // NN+1
    int*   bsum   = rowptr + NN + 1;                   // pad to 8B align
    u64*   edges  = (u64*)(((size_t)(bsum + 256) + 7) & ~(size_t)7);  // NE * 8B

    hipMemsetAsync(cnt, 0, sizeof(int) * 2 * NN, stream);
    hipMemsetAsync(sums1, 0, sizeof(float) * (2 * D1 + 2 * D2), stream);

    // ---- CSR build ----
    cnt_k<<<(NE + 255) / 256, 256, 0, stream>>>(dst, cnt);
    make_dis_k<<<(NN + 255) / 256, 256, 0, stream>>>(cnt, dis);
    scan1_k<<<NB_SCAN, SCAN_CHUNK, 0, stream>>>(cnt, rowptr, bsum);
    scan2_k<<<1, 64, 0, stream>>>(bsum);
    scan3_k<<<(NN + 255) / 256, 256, 0, stream>>>(rowptr, bsum);
    fill_k<<<(NE + 255) / 256, 256, 0, stream>>>(src, dst, rowptr, dis, cur, edges);

    // ---- layer 1 ----
    gemm_k<128, false><<<(NN + 63) / 64, 256, 0, stream>>>(x, W1, nullptr, xwb);
    agg_k<128><<<2048, 256, 0, stream>>>(rowptr, edges, dis, xwb, b1, agg1, sums1, ssq1);
    bncoef_k<<<1, 128, 0, stream>>>(sums1, ssq1, g1, be1, coef1, D1);

    // ---- layer 2 (BN1+ReLU fused into GEMM input load) ----
    gemm_k<64, true><<<(NN + 63) / 64, 256, 0, stream>>>(agg1, W2, coef1, xwb);
    agg_k<64><<<2048, 256, 0, stream>>>(rowptr, edges, dis, xwb, b2, agg2, sums2, ssq2);
    bncoef_k<<<1, 64, 0, stream>>>(sums2, ssq2, g2, be2, coef2, D2);

    // ---- final projection (BN2+ReLU fused) ----
    final_k<<<(NN * 64 + 255) / 256, 256, 0, stream>>>(agg2, coef2, Wf, bf, out);
}

// Round 6
// 515.746 us; speedup vs baseline: 1.1142x; 1.1142x over previous
//
#include <hip/hip_runtime.h>

#define NN 100000
#define NE 1600000
#define D1 128
#define D2 64
#define BN_EPS 1e-5f
#define SCAN_CHUNK 512
#define NB_SCAN ((NN + SCAN_CHUNK - 1) / SCAN_CHUNK)   // 196

typedef unsigned int uint32;
typedef unsigned long long u64;
typedef unsigned short ushort;
typedef __attribute__((ext_vector_type(8))) short bf16x8;
typedef __attribute__((ext_vector_type(4))) float f32x4;

// ---- bf16 helpers (RNE) ----
__device__ __forceinline__ ushort f2bf1(float f) {
    uint32 u = __float_as_uint(f);
    return (ushort)((u + 0x7FFFu + ((u >> 16) & 1u)) >> 16);
}
__device__ __forceinline__ float bf_lo(uint32 v) { return __uint_as_float(v << 16); }
__device__ __forceinline__ float bf_hi(uint32 v) { return __uint_as_float(v & 0xFFFF0000u); }

// ---------------- degree count (int atomics, from dst) ----------------
__global__ __launch_bounds__(256) void cnt_k(const int* __restrict__ dst,
                                             int* __restrict__ cnt) {
    int i = blockIdx.x * 256 + threadIdx.x;
    if (i < NE) atomicAdd(&cnt[dst[i]], 1);
}

// ---------------- dis = rsqrt(cnt+1) ----------------
__global__ __launch_bounds__(256) void make_dis_k(const int* __restrict__ cnt,
                                                  float* __restrict__ dis) {
    int i = blockIdx.x * 256 + threadIdx.x;
    if (i < NN) dis[i] = rsqrtf((float)cnt[i] + 1.0f);
}

// ---------------- prefix scan (3 kernels) ----------------
__global__ __launch_bounds__(SCAN_CHUNK) void scan1_k(const int* __restrict__ cnt,
                                                      int* __restrict__ rowptr,
                                                      int* __restrict__ bsum) {
    __shared__ int sh[SCAN_CHUNK];
    int tid = threadIdx.x;
    int g = blockIdx.x * SCAN_CHUNK + tid;
    int v = (g < NN) ? cnt[g] : 0;
    sh[tid] = v;
    __syncthreads();
    for (int o = 1; o < SCAN_CHUNK; o <<= 1) {
        int t = (tid >= o) ? sh[tid - o] : 0;
        __syncthreads();
        sh[tid] += t;
        __syncthreads();
    }
    if (g < NN) rowptr[g] = sh[tid] - v;
    if (tid == SCAN_CHUNK - 1) bsum[blockIdx.x] = sh[tid];
}

__global__ void scan2_k(int* __restrict__ bsum) {
    if (threadIdx.x == 0 && blockIdx.x == 0) {
        int a = 0;
        for (int i = 0; i < NB_SCAN; ++i) { int t = bsum[i]; bsum[i] = a; a += t; }
    }
}

__global__ __launch_bounds__(256) void scan3_k(int* __restrict__ rowptr,
                                               const int* __restrict__ bsum) {
    int g = blockIdx.x * 256 + threadIdx.x;
    if (g < NN) rowptr[g] += bsum[g >> 9];
    if (g == 0) rowptr[NN] = NE;
}

// ---------------- CSR fill: slot-atomic per edge; pack (src, weight) in 8B ----------------
__global__ __launch_bounds__(256) void fill_k(const int* __restrict__ src,
                                              const int* __restrict__ dst,
                                              const int* __restrict__ rowptr,
                                              const float* __restrict__ dis,
                                              int* __restrict__ cur,
                                              u64* __restrict__ edges) {
    int e = blockIdx.x * 256 + threadIdx.x;
    if (e >= NE) return;
    int d = dst[e];
    int s = src[e];
    int p = rowptr[d] + atomicAdd(&cur[d], 1);
    u64 pk = ((u64)__float_as_uint(dis[s] * dis[d]) << 32) | (uint32)s;
    edges[p] = pk;
}

// ---------------- BN coefficients ----------------
__global__ void bncoef_k(const float* __restrict__ sums, const float* __restrict__ ssq,
                         const float* __restrict__ g, const float* __restrict__ beta,
                         float* __restrict__ coef, int dim) {
    int c = threadIdx.x;
    if (c >= dim) return;
    float m = sums[c] * (1.0f / NN);
    float var = ssq[c] * (1.0f / NN) - m * m;
    float sc = g[c] * rsqrtf(var + BN_EPS);
    coef[c] = sc;
    coef[dim + c] = beta[c] - m * sc;
}

// ---------------- W transpose + bf16 convert: Wt[c][k] = bf16(W[k][c]) ----------------
__global__ __launch_bounds__(256) void wt_k(const float* __restrict__ W1,
                                            const float* __restrict__ W2,
                                            ushort* __restrict__ wt1,
                                            ushort* __restrict__ wt2) {
    int i = blockIdx.x * 256 + threadIdx.x;
    if (i < 128 * 128) {
        int c = i >> 7, k = i & 127;
        wt1[i] = f2bf1(W1[k * 128 + c]);
    } else if (i < 128 * 128 + 64 * 128) {
        int o = i - 128 * 128;
        int c = o >> 7, k = o & 127;
        wt2[o] = f2bf1(W2[k * 64 + c]);
    }
}

// ---------------- MFMA GEMM: Yb[NN,OUT](bf16) = f(X)[NN,128] @ W[128,OUT] ----------------
// 4 waves/block, each wave: 16 rows x OUT cols via 16x16x32 bf16 MFMA.
// Wt is W^T in bf16 [OUT][128], read from global (L1/L2-hot, 32KB max).
template<int OUT, bool FUSE_BN>
__global__ __launch_bounds__(256) void mgemm_k(const float* __restrict__ X,
                                               const ushort* __restrict__ Wt,
                                               const float* __restrict__ coef,
                                               ushort* __restrict__ Yb) {
    const int lane = threadIdx.x & 63;
    const int wv = threadIdx.x >> 6;
    const int row0 = blockIdx.x * 64 + wv * 16;
    const int m = lane & 15;     // A row within strip / D col within tile
    const int kg = lane >> 4;    // k-group (0..3)
    const int rowA = min(row0 + m, NN - 1);
    f32x4 acc[OUT / 16];
    #pragma unroll
    for (int t = 0; t < OUT / 16; ++t) acc[t] = (f32x4){0.f, 0.f, 0.f, 0.f};

    #pragma unroll
    for (int kc = 0; kc < 128; kc += 32) {
        const int k0 = kc + kg * 8;
        float4 xa = *(const float4*)(X + (size_t)rowA * 128 + k0);
        float4 xb = *(const float4*)(X + (size_t)rowA * 128 + k0 + 4);
        if constexpr (FUSE_BN) {
            float4 sa = *(const float4*)(coef + k0);
            float4 sb = *(const float4*)(coef + k0 + 4);
            float4 ha = *(const float4*)(coef + 128 + k0);
            float4 hb = *(const float4*)(coef + 128 + k0 + 4);
            xa.x = fmaxf(fmaf(xa.x, sa.x, ha.x), 0.f);
            xa.y = fmaxf(fmaf(xa.y, sa.y, ha.y), 0.f);
            xa.z = fmaxf(fmaf(xa.z, sa.z, ha.z), 0.f);
            xa.w = fmaxf(fmaf(xa.w, sa.w, ha.w), 0.f);
            xb.x = fmaxf(fmaf(xb.x, sb.x, hb.x), 0.f);
            xb.y = fmaxf(fmaf(xb.y, sb.y, hb.y), 0.f);
            xb.z = fmaxf(fmaf(xb.z, sb.z, hb.z), 0.f);
            xb.w = fmaxf(fmaf(xb.w, sb.w, hb.w), 0.f);
        }
        bf16x8 af;
        af[0] = (short)f2bf1(xa.x); af[1] = (short)f2bf1(xa.y);
        af[2] = (short)f2bf1(xa.z); af[3] = (short)f2bf1(xa.w);
        af[4] = (short)f2bf1(xb.x); af[5] = (short)f2bf1(xb.y);
        af[6] = (short)f2bf1(xb.z); af[7] = (short)f2bf1(xb.w);
        #pragma unroll
        for (int t = 0; t < OUT / 16; ++t) {
            bf16x8 bf = *(const bf16x8*)(Wt + (size_t)(t * 16 + m) * 128 + k0);
            acc[t] = __builtin_amdgcn_mfma_f32_16x16x32_bf16(af, bf, acc[t], 0, 0, 0);
        }
    }
    // D layout: col = lane&15 (=m), row = kg*4 + r
    #pragma unroll
    for (int t = 0; t < OUT / 16; ++t) {
        #pragma unroll
        for (int r = 0; r < 4; ++r) {
            int rr = row0 + kg * 4 + r;
            if (rr < NN) Yb[(size_t)rr * OUT + t * 16 + m] = f2bf1(acc[t][r]);
        }
    }
}

// ---------------- agg layer1 (D=128): one wave per node, 8-deep gather pipeline ----------------
__global__ __launch_bounds__(256) void agg128_k(const int* __restrict__ rowptr,
                                                const u64* __restrict__ edges,
                                                const float* __restrict__ dis,
                                                const uint32* __restrict__ xwb,
                                                const float* __restrict__ b,
                                                float* __restrict__ agg,
                                                float* __restrict__ sums,
                                                float* __restrict__ ssq) {
    const int lane = threadIdx.x & 63;
    const int wid = (blockIdx.x * 256 + threadIdx.x) >> 6;
    const int nwaves = gridDim.x * 4;
    float s0 = 0.f, s1 = 0.f, q0 = 0.f, q1 = 0.f;
    const float bc0 = b[lane * 2], bc1 = b[lane * 2 + 1];

    for (int n = wid; n < NN; n += nwaves) {
        const int beg = rowptr[n], end = rowptr[n + 1];
        const float dn = dis[n];
        float ax = 0.f, ay = 0.f;
        int e = beg;
        for (; e + 8 <= end; e += 8) {
            u64 ed[8]; uint32 vv[8]; float ww[8];
            #pragma unroll
            for (int j = 0; j < 8; ++j) ed[j] = edges[e + j];
            #pragma unroll
            for (int j = 0; j < 8; ++j) {
                vv[j] = xwb[(size_t)(uint32)ed[j] * 64 + lane];
                ww[j] = __uint_as_float((uint32)(ed[j] >> 32));
            }
            #pragma unroll
            for (int j = 0; j < 8; ++j) {
                ax = fmaf(bf_lo(vv[j]), ww[j], ax);
                ay = fmaf(bf_hi(vv[j]), ww[j], ay);
            }
        }
        for (; e < end; ++e) {
            u64 ed = edges[e];
            float w = __uint_as_float((uint32)(ed >> 32));
            uint32 v = xwb[(size_t)(uint32)ed * 64 + lane];
            ax = fmaf(bf_lo(v), w, ax);
            ay = fmaf(bf_hi(v), w, ay);
        }
        float sl = dn * dn;  // self-loop norm 1/(deg+1)
        uint32 xv = xwb[(size_t)n * 64 + lane];
        ax = fmaf(bf_lo(xv), sl, ax) + bc0;
        ay = fmaf(bf_hi(xv), sl, ay) + bc1;
        u64 o = ((u64)__float_as_uint(ay) << 32) | __float_as_uint(ax);
        __builtin_nontemporal_store(o, (u64*)&agg[(size_t)n * 128 + lane * 2]);
        s0 += ax; q0 = fmaf(ax, ax, q0);
        s1 += ay; q1 = fmaf(ay, ay, q1);
    }

    __shared__ float ls[256];
    ls[threadIdx.x] = 0.f;  // 256 = 2*D1
    __syncthreads();
    atomicAdd(&ls[lane * 2], s0);
    atomicAdd(&ls[lane * 2 + 1], s1);
    atomicAdd(&ls[128 + lane * 2], q0);
    atomicAdd(&ls[128 + lane * 2 + 1], q1);
    __syncthreads();
    if (threadIdx.x < 128) atomicAdd(&sums[threadIdx.x], ls[threadIdx.x]);
    else atomicAdd(&ssq[threadIdx.x - 128], ls[threadIdx.x]);
}

// ---------------- agg layer2 (D=64): half-wave per edge (2 edges in flight per gather) ----------------
__global__ __launch_bounds__(256) void agg64_k(const int* __restrict__ rowptr,
                                               const u64* __restrict__ edges,
                                               const float* __restrict__ dis,
                                               const uint32* __restrict__ xwb,  // 32 uint32/row
                                               const float* __restrict__ b,
                                               float* __restrict__ agg,
                                               float* __restrict__ sums,
                                               float* __restrict__ ssq) {
    const int lane = threadIdx.x & 63;
    const int half = lane >> 5;       // 0 or 1
    const int sl = lane & 31;         // covers cols {2sl, 2sl+1}
    const int wid = (blockIdx.x * 256 + threadIdx.x) >> 6;
    const int nwaves = gridDim.x * 4;
    float s0 = 0.f, s1 = 0.f, q0 = 0.f, q1 = 0.f;
    const float bc0 = b[sl * 2], bc1 = b[sl * 2 + 1];

    for (int n = wid; n < NN; n += nwaves) {
        const int beg = rowptr[n], end = rowptr[n + 1];
        const float dn = dis[n];
        float ax = 0.f, ay = 0.f;
        int e = beg;
        // 16 edges per batch: each half handles 8 (interleaved)
        for (; e + 16 <= end; e += 16) {
            u64 ed[8]; uint32 vv[8]; float ww[8];
            #pragma unroll
            for (int j = 0; j < 8; ++j) ed[j] = edges[e + 2 * j + half];
            #pragma unroll
            for (int j = 0; j < 8; ++j) {
                vv[j] = xwb[(size_t)(uint32)ed[j] * 32 + sl];
                ww[j] = __uint_as_float((uint32)(ed[j] >> 32));
            }
            #pragma unroll
            for (int j = 0; j < 8; ++j) {
                ax = fmaf(bf_lo(vv[j]), ww[j], ax);
                ay = fmaf(bf_hi(vv[j]), ww[j], ay);
            }
        }
        for (; e + 2 <= end; e += 2) {
            u64 ed = edges[e + half];
            float w = __uint_as_float((uint32)(ed >> 32));
            uint32 v = xwb[(size_t)(uint32)ed * 32 + sl];
            ax = fmaf(bf_lo(v), w, ax);
            ay = fmaf(bf_hi(v), w, ay);
        }
        if (e < end && half == 0) {  // odd leftover: half 0 only
            u64 ed = edges[e];
            float w = __uint_as_float((uint32)(ed >> 32));
            uint32 v = xwb[(size_t)(uint32)ed * 32 + sl];
            ax = fmaf(bf_lo(v), w, ax);
            ay = fmaf(bf_hi(v), w, ay);
        }
        // combine halves (lane l += lane l+32)
        ax += __shfl_down(ax, 32);
        ay += __shfl_down(ay, 32);
        if (half == 0) {
            float slf = dn * dn;
            uint32 xv = xwb[(size_t)n * 32 + sl];
            ax = fmaf(bf_lo(xv), slf, ax) + bc0;
            ay = fmaf(bf_hi(xv), slf, ay) + bc1;
            u64 o = ((u64)__float_as_uint(ay) << 32) | __float_as_uint(ax);
            __builtin_nontemporal_store(o, (u64*)&agg[(size_t)n * 64 + sl * 2]);
            s0 += ax; q0 = fmaf(ax, ax, q0);
            s1 += ay; q1 = fmaf(ay, ay, q1);
        }
    }

    __shared__ float ls[128];  // 2*D2
    if (threadIdx.x < 128) ls[threadIdx.x] = 0.f;
    __syncthreads();
    if (half == 0) {
        atomicAdd(&ls[sl * 2], s0);
        atomicAdd(&ls[sl * 2 + 1], s1);
        atomicAdd(&ls[64 + sl * 2], q0);
        atomicAdd(&ls[64 + sl * 2 + 1], q1);
    }
    __syncthreads();
    if (threadIdx.x < 64) atomicAdd(&sums[threadIdx.x], ls[threadIdx.x]);
    else if (threadIdx.x < 128) atomicAdd(&ssq[threadIdx.x - 64], ls[threadIdx.x]);
}

// ---------------- final: out = relu(BN2(h2)) @ Wf + bf ----------------
__global__ __launch_bounds__(256) void final_k(const float* __restrict__ h,
                                               const float* __restrict__ coef,
                                               const float* __restrict__ Wf,
                                               const float* __restrict__ bf,
                                               float* __restrict__ out) {
    int wid = (blockIdx.x * 256 + threadIdx.x) >> 6;
    int lane = threadIdx.x & 63;
    if (wid >= NN) return;
    float v = fmaxf(fmaf(h[(size_t)wid * 64 + lane], coef[lane], coef[64 + lane]), 0.f)
              * Wf[lane];
    #pragma unroll
    for (int o = 32; o > 0; o >>= 1) v += __shfl_down(v, o);
    if (lane == 0) out[wid] = v + bf[0];
}

extern "C" void kernel_launch(void* const* d_in, const int* in_sizes, int n_in,
                              void* d_out, int out_size, void* d_ws, size_t ws_size,
                              hipStream_t stream) {
    const float* x   = (const float*)d_in[0];
    const int*   ei  = (const int*)d_in[1];
    const int*   src = ei;
    const int*   dst = ei + NE;
    const float* W1  = (const float*)d_in[2];
    const float* b1  = (const float*)d_in[3];
    const float* g1  = (const float*)d_in[4];
    const float* be1 = (const float*)d_in[5];
    const float* W2  = (const float*)d_in[6];
    const float* b2  = (const float*)d_in[7];
    const float* g2  = (const float*)d_in[8];
    const float* be2 = (const float*)d_in[9];
    const float* Wf  = (const float*)d_in[10];
    const float* bf  = (const float*)d_in[11];
    float* out = (float*)d_out;

    // ---- workspace layout ----
    uint32* xwb  = (uint32*)d_ws;                      // NN*64 uint32 (bf16 pairs, 25.6MB)
    float* agg1  = (float*)(xwb + (size_t)NN * 64);    // NN*128 f32
    float* agg2  = agg1  + (size_t)NN * D1;            // NN*64 f32
    float* dis   = agg2  + (size_t)NN * D2;            // NN
    float* sums1 = dis   + NN;                         // 128
    float* ssq1  = sums1 + D1;
    float* sums2 = ssq1  + D1;
    float* ssq2  = sums2 + D2;
    float* coef1 = ssq2  + D2;                         // 256
    float* coef2 = coef1 + 2 * D1;                     // 128
    ushort* wt1  = (ushort*)(coef2 + 2 * D2);          // 128*128 bf16 (W1^T)
    ushort* wt2  = wt1 + 128 * 128;                    // 64*128 bf16 (W2^T)
    int*   cnt    = (int*)(wt2 + 64 * 128);            // NN
    int*   cur    = cnt + NN;                          // NN
    int*   rowptr = cur + NN;                          // NN+1
    int*   bsum   = rowptr + NN + 1;                   // pad
    u64*   edges  = (u64*)(((size_t)(bsum + 256) + 7) & ~(size_t)7);  // NE * 8B

    hipMemsetAsync(cnt, 0, sizeof(int) * 2 * NN, stream);
    hipMemsetAsync(sums1, 0, sizeof(float) * (2 * D1 + 2 * D2), stream);

    // ---- CSR build + weight prep ----
    cnt_k<<<(NE + 255) / 256, 256, 0, stream>>>(dst, cnt);
    make_dis_k<<<(NN + 255) / 256, 256, 0, stream>>>(cnt, dis);
    scan1_k<<<NB_SCAN, SCAN_CHUNK, 0, stream>>>(cnt, rowptr, bsum);
    scan2_k<<<1, 64, 0, stream>>>(bsum);
    scan3_k<<<(NN + 255) / 256, 256, 0, stream>>>(rowptr, bsum);
    fill_k<<<(NE + 255) / 256, 256, 0, stream>>>(src, dst, rowptr, dis, cur, edges);
    wt_k<<<(128 * 128 + 64 * 128 + 255) / 256, 256, 0, stream>>>(W1, W2, wt1, wt2);

    // ---- layer 1 ----
    mgemm_k<128, false><<<(NN + 63) / 64, 256, 0, stream>>>(x, wt1, nullptr, (ushort*)xwb);
    agg128_k<<<4096, 256, 0, stream>>>(rowptr, edges, dis, xwb, b1, agg1, sums1, ssq1);
    bncoef_k<<<1, 128, 0, stream>>>(sums1, ssq1, g1, be1, coef1, D1);

    // ---- layer 2 (BN1+ReLU fused into GEMM input load) ----
    mgemm_k<64, true><<<(NN + 63) / 64, 256, 0, stream>>>(agg1, wt2, coef1, (ushort*)xwb);
    agg64_k<<<4096, 256, 0, stream>>>(rowptr, edges, dis, xwb, b2, agg2, sums2, ssq2);
    bncoef_k<<<1, 64, 0, stream>>>(sums2, ssq2, g2, be2, coef2, D2);

    // ---- final projection (BN2+ReLU fused) ----
    final_k<<<(NN * 64 + 255) / 256, 256, 0, stream>>>(agg2, coef2, Wf, bf, out);
}

// Round 7
// 446.695 us; speedup vs baseline: 1.2864x; 1.1546x over previous
//
#include <hip/hip_runtime.h>

#define NN 100000
#define NE 1600000
#define D1 128
#define D2 64
#define BN_EPS 1e-5f
#define SCAN_CHUNK 512
#define NB_SCAN ((NN + SCAN_CHUNK - 1) / SCAN_CHUNK)   // 196

typedef unsigned int uint32;
typedef unsigned long long u64;
typedef unsigned short ushort;
typedef __attribute__((ext_vector_type(8))) short bf16x8;
typedef __attribute__((ext_vector_type(4))) float f32x4;

// ---- bf16 helpers (RNE) ----
__device__ __forceinline__ ushort f2bf1(float f) {
    uint32 u = __float_as_uint(f);
    return (ushort)((u + 0x7FFFu + ((u >> 16) & 1u)) >> 16);
}
__device__ __forceinline__ uint32 f2bf_pair(float a, float b) {
    uint32 ua = __float_as_uint(a), ub = __float_as_uint(b);
    ua = (ua + 0x7FFFu + ((ua >> 16) & 1u)) >> 16;
    ub = (ub + 0x7FFFu + ((ub >> 16) & 1u)) >> 16;
    return ua | (ub << 16);
}
__device__ __forceinline__ float bf_lo(uint32 v) { return __uint_as_float(v << 16); }
__device__ __forceinline__ float bf_hi(uint32 v) { return __uint_as_float(v & 0xFFFF0000u); }

// ---------------- degree count (int atomics, from dst) ----------------
__global__ __launch_bounds__(256) void cnt_k(const int* __restrict__ dst,
                                             int* __restrict__ cnt) {
    int i = blockIdx.x * 256 + threadIdx.x;
    if (i < NE) atomicAdd(&cnt[dst[i]], 1);
}

// ---------------- dis = rsqrt(cnt+1) ----------------
__global__ __launch_bounds__(256) void make_dis_k(const int* __restrict__ cnt,
                                                  float* __restrict__ dis) {
    int i = blockIdx.x * 256 + threadIdx.x;
    if (i < NN) dis[i] = rsqrtf((float)cnt[i] + 1.0f);
}

// ---------------- prefix scan (3 kernels) ----------------
__global__ __launch_bounds__(SCAN_CHUNK) void scan1_k(const int* __restrict__ cnt,
                                                      int* __restrict__ rowptr,
                                                      int* __restrict__ bsum) {
    __shared__ int sh[SCAN_CHUNK];
    int tid = threadIdx.x;
    int g = blockIdx.x * SCAN_CHUNK + tid;
    int v = (g < NN) ? cnt[g] : 0;
    sh[tid] = v;
    __syncthreads();
    for (int o = 1; o < SCAN_CHUNK; o <<= 1) {
        int t = (tid >= o) ? sh[tid - o] : 0;
        __syncthreads();
        sh[tid] += t;
        __syncthreads();
    }
    if (g < NN) rowptr[g] = sh[tid] - v;
    if (tid == SCAN_CHUNK - 1) bsum[blockIdx.x] = sh[tid];
}

__global__ void scan2_k(int* __restrict__ bsum) {
    if (threadIdx.x == 0 && blockIdx.x == 0) {
        int a = 0;
        for (int i = 0; i < NB_SCAN; ++i) { int t = bsum[i]; bsum[i] = a; a += t; }
    }
}

__global__ __launch_bounds__(256) void scan3_k(int* __restrict__ rowptr,
                                               const int* __restrict__ bsum) {
    int g = blockIdx.x * 256 + threadIdx.x;
    if (g < NN) rowptr[g] += bsum[g >> 9];
    if (g == 0) rowptr[NN] = NE;
}

// ---------------- CSR fill: slot-atomic per edge (separate src / weight streams) ----------------
__global__ __launch_bounds__(256) void fill_k(const int* __restrict__ src,
                                              const int* __restrict__ dst,
                                              const int* __restrict__ rowptr,
                                              const float* __restrict__ dis,
                                              int* __restrict__ cur,
                                              int* __restrict__ esrc,
                                              float* __restrict__ ew) {
    int e = blockIdx.x * 256 + threadIdx.x;
    if (e >= NE) return;
    int d = dst[e];
    int s = src[e];
    int p = rowptr[d] + atomicAdd(&cur[d], 1);
    esrc[p] = s;
    ew[p] = dis[s] * dis[d];
}

// ---------------- BN coefficients ----------------
__global__ void bncoef_k(const float* __restrict__ sums, const float* __restrict__ ssq,
                         const float* __restrict__ g, const float* __restrict__ beta,
                         float* __restrict__ coef, int dim) {
    int c = threadIdx.x;
    if (c >= dim) return;
    float m = sums[c] * (1.0f / NN);
    float var = ssq[c] * (1.0f / NN) - m * m;
    float sc = g[c] * rsqrtf(var + BN_EPS);
    coef[c] = sc;
    coef[dim + c] = beta[c] - m * sc;
}

// ---------------- W transpose + bf16 convert: Wt[c][k] = bf16(W[k][c]) ----------------
__global__ __launch_bounds__(256) void wt_k(const float* __restrict__ W1,
                                            const float* __restrict__ W2,
                                            ushort* __restrict__ wt1,
                                            ushort* __restrict__ wt2) {
    int i = blockIdx.x * 256 + threadIdx.x;
    if (i < 128 * 128) {
        int c = i >> 7, k = i & 127;
        wt1[i] = f2bf1(W1[k * 128 + c]);
    } else if (i < 128 * 128 + 64 * 128) {
        int o = i - 128 * 128;
        int c = o >> 7, k = o & 127;
        wt2[o] = f2bf1(W2[k * 64 + c]);
    }
}

// ---------------- MFMA GEMM: Yb[NN,OUT](bf16) = f(X)[NN,128] @ W[128,OUT] ----------------
// 4 waves/block, each wave: 16 rows x OUT cols via 16x16x32 bf16 MFMA.
// BF16BN: X is bf16 (pairs) + fused BN(coef)+ReLU on load; else X is f32, no BN.
template<int OUT, bool BF16BN>
__global__ __launch_bounds__(256) void mgemm_k(const void* __restrict__ Xv,
                                               const ushort* __restrict__ Wt,
                                               const float* __restrict__ coef,
                                               ushort* __restrict__ Yb) {
    const int lane = threadIdx.x & 63;
    const int wv = threadIdx.x >> 6;
    const int row0 = blockIdx.x * 64 + wv * 16;
    const int m = lane & 15;     // A row within strip / D col within tile
    const int kg = lane >> 4;    // k-group (0..3)
    const int rowA = min(row0 + m, NN - 1);
    f32x4 acc[OUT / 16];
    #pragma unroll
    for (int t = 0; t < OUT / 16; ++t) acc[t] = (f32x4){0.f, 0.f, 0.f, 0.f};

    #pragma unroll
    for (int kc = 0; kc < 128; kc += 32) {
        const int k0 = kc + kg * 8;
        float xs[8];
        if constexpr (BF16BN) {
            const ushort* Xb = (const ushort*)Xv;
            uint4 raw = *(const uint4*)(Xb + (size_t)rowA * 128 + k0);
            xs[0] = bf_lo(raw.x); xs[1] = bf_hi(raw.x);
            xs[2] = bf_lo(raw.y); xs[3] = bf_hi(raw.y);
            xs[4] = bf_lo(raw.z); xs[5] = bf_hi(raw.z);
            xs[6] = bf_lo(raw.w); xs[7] = bf_hi(raw.w);
            float4 sa = *(const float4*)(coef + k0);
            float4 sb = *(const float4*)(coef + k0 + 4);
            float4 ha = *(const float4*)(coef + 128 + k0);
            float4 hb = *(const float4*)(coef + 128 + k0 + 4);
            xs[0] = fmaxf(fmaf(xs[0], sa.x, ha.x), 0.f);
            xs[1] = fmaxf(fmaf(xs[1], sa.y, ha.y), 0.f);
            xs[2] = fmaxf(fmaf(xs[2], sa.z, ha.z), 0.f);
            xs[3] = fmaxf(fmaf(xs[3], sa.w, ha.w), 0.f);
            xs[4] = fmaxf(fmaf(xs[4], sb.x, hb.x), 0.f);
            xs[5] = fmaxf(fmaf(xs[5], sb.y, hb.y), 0.f);
            xs[6] = fmaxf(fmaf(xs[6], sb.z, hb.z), 0.f);
            xs[7] = fmaxf(fmaf(xs[7], sb.w, hb.w), 0.f);
        } else {
            const float* X = (const float*)Xv;
            float4 xa = *(const float4*)(X + (size_t)rowA * 128 + k0);
            float4 xb = *(const float4*)(X + (size_t)rowA * 128 + k0 + 4);
            xs[0] = xa.x; xs[1] = xa.y; xs[2] = xa.z; xs[3] = xa.w;
            xs[4] = xb.x; xs[5] = xb.y; xs[6] = xb.z; xs[7] = xb.w;
        }
        bf16x8 af;
        #pragma unroll
        for (int i = 0; i < 8; ++i) af[i] = (short)f2bf1(xs[i]);
        #pragma unroll
        for (int t = 0; t < OUT / 16; ++t) {
            bf16x8 bfr = *(const bf16x8*)(Wt + (size_t)(t * 16 + m) * 128 + k0);
            acc[t] = __builtin_amdgcn_mfma_f32_16x16x32_bf16(af, bfr, acc[t], 0, 0, 0);
        }
    }
    // D layout: col = lane&15 (=m), row = kg*4 + r
    #pragma unroll
    for (int t = 0; t < OUT / 16; ++t) {
        #pragma unroll
        for (int r = 0; r < 4; ++r) {
            int rr = row0 + kg * 4 + r;
            if (rr < NN) Yb[(size_t)rr * OUT + t * 16 + m] = f2bf1(acc[t][r]);
        }
    }
}

// ---------------- agg layer1 (D=128): one wave/node, 8-deep, bf16 in AND out ----------------
__global__ __launch_bounds__(256) void agg128_k(const int* __restrict__ rowptr,
                                                const int* __restrict__ esrc,
                                                const float* __restrict__ ew,
                                                const float* __restrict__ dis,
                                                const uint32* __restrict__ xwb,
                                                const float* __restrict__ b,
                                                uint32* __restrict__ agg1b,
                                                float* __restrict__ sums,
                                                float* __restrict__ ssq) {
    const int lane = threadIdx.x & 63;
    const int wid = (blockIdx.x * 256 + threadIdx.x) >> 6;
    const int nwaves = gridDim.x * 4;
    float s0 = 0.f, s1 = 0.f, q0 = 0.f, q1 = 0.f;
    const float bc0 = b[lane * 2], bc1 = b[lane * 2 + 1];

    for (int n = wid; n < NN; n += nwaves) {
        const int beg = rowptr[n], end = rowptr[n + 1];
        const float dn = dis[n];
        float ax = 0.f, ay = 0.f;
        int e = beg;
        for (; e + 8 <= end; e += 8) {
            int idx[8]; float w[8]; uint32 vv[8];
            #pragma unroll
            for (int j = 0; j < 8; ++j) idx[j] = esrc[e + j];
            #pragma unroll
            for (int j = 0; j < 8; ++j) w[j] = ew[e + j];
            #pragma unroll
            for (int j = 0; j < 8; ++j)
                vv[j] = xwb[(size_t)idx[j] * 64 + lane];
            #pragma unroll
            for (int j = 0; j < 8; ++j) {
                ax = fmaf(bf_lo(vv[j]), w[j], ax);
                ay = fmaf(bf_hi(vv[j]), w[j], ay);
            }
        }
        for (; e < end; ++e) {
            int s = esrc[e];
            float w = ew[e];
            uint32 v = xwb[(size_t)s * 64 + lane];
            ax = fmaf(bf_lo(v), w, ax);
            ay = fmaf(bf_hi(v), w, ay);
        }
        float sl = dn * dn;  // self-loop norm 1/(deg+1)
        uint32 xv = xwb[(size_t)n * 64 + lane];
        ax = fmaf(bf_lo(xv), sl, ax) + bc0;
        ay = fmaf(bf_hi(xv), sl, ay) + bc1;
        agg1b[(size_t)n * 64 + lane] = f2bf_pair(ax, ay);
        s0 += ax; q0 = fmaf(ax, ax, q0);
        s1 += ay; q1 = fmaf(ay, ay, q1);
    }

    __shared__ float ls[256];
    ls[threadIdx.x] = 0.f;  // 256 = 2*D1
    __syncthreads();
    atomicAdd(&ls[lane * 2], s0);
    atomicAdd(&ls[lane * 2 + 1], s1);
    atomicAdd(&ls[128 + lane * 2], q0);
    atomicAdd(&ls[128 + lane * 2 + 1], q1);
    __syncthreads();
    if (threadIdx.x < 128) atomicAdd(&sums[threadIdx.x], ls[threadIdx.x]);
    else atomicAdd(&ssq[threadIdx.x - 128], ls[threadIdx.x]);
}

// ---------------- agg layer2 (D=64): half-wave per edge ----------------
__global__ __launch_bounds__(256) void agg64_k(const int* __restrict__ rowptr,
                                               const int* __restrict__ esrc,
                                               const float* __restrict__ ew,
                                               const float* __restrict__ dis,
                                               const uint32* __restrict__ xwb,  // 32 uint32/row
                                               const float* __restrict__ b,
                                               float* __restrict__ agg,
                                               float* __restrict__ sums,
                                               float* __restrict__ ssq) {
    const int lane = threadIdx.x & 63;
    const int half = lane >> 5;       // 0 or 1
    const int sl = lane & 31;         // covers cols {2sl, 2sl+1}
    const int wid = (blockIdx.x * 256 + threadIdx.x) >> 6;
    const int nwaves = gridDim.x * 4;
    float s0 = 0.f, s1 = 0.f, q0 = 0.f, q1 = 0.f;
    const float bc0 = b[sl * 2], bc1 = b[sl * 2 + 1];

    for (int n = wid; n < NN; n += nwaves) {
        const int beg = rowptr[n], end = rowptr[n + 1];
        const float dn = dis[n];
        float ax = 0.f, ay = 0.f;
        int e = beg;
        for (; e + 16 <= end; e += 16) {
            int idx[8]; float w[8]; uint32 vv[8];
            #pragma unroll
            for (int j = 0; j < 8; ++j) idx[j] = esrc[e + 2 * j + half];
            #pragma unroll
            for (int j = 0; j < 8; ++j) w[j] = ew[e + 2 * j + half];
            #pragma unroll
            for (int j = 0; j < 8; ++j)
                vv[j] = xwb[(size_t)idx[j] * 32 + sl];
            #pragma unroll
            for (int j = 0; j < 8; ++j) {
                ax = fmaf(bf_lo(vv[j]), w[j], ax);
                ay = fmaf(bf_hi(vv[j]), w[j], ay);
            }
        }
        for (; e + 2 <= end; e += 2) {
            int s = esrc[e + half];
            float w = ew[e + half];
            uint32 v = xwb[(size_t)s * 32 + sl];
            ax = fmaf(bf_lo(v), w, ax);
            ay = fmaf(bf_hi(v), w, ay);
        }
        if (e < end && half == 0) {
            int s = esrc[e];
            float w = ew[e];
            uint32 v = xwb[(size_t)s * 32 + sl];
            ax = fmaf(bf_lo(v), w, ax);
            ay = fmaf(bf_hi(v), w, ay);
        }
        ax += __shfl_down(ax, 32);
        ay += __shfl_down(ay, 32);
        if (half == 0) {
            float slf = dn * dn;
            uint32 xv = xwb[(size_t)n * 32 + sl];
            ax = fmaf(bf_lo(xv), slf, ax) + bc0;
            ay = fmaf(bf_hi(xv), slf, ay) + bc1;
            *(float2*)&agg[(size_t)n * 64 + sl * 2] = make_float2(ax, ay);
            s0 += ax; q0 = fmaf(ax, ax, q0);
            s1 += ay; q1 = fmaf(ay, ay, q1);
        }
    }

    __shared__ float ls[128];  // 2*D2
    if (threadIdx.x < 128) ls[threadIdx.x] = 0.f;
    __syncthreads();
    if (half == 0) {
        atomicAdd(&ls[sl * 2], s0);
        atomicAdd(&ls[sl * 2 + 1], s1);
        atomicAdd(&ls[64 + sl * 2], q0);
        atomicAdd(&ls[64 + sl * 2 + 1], q1);
    }
    __syncthreads();
    if (threadIdx.x < 64) atomicAdd(&sums[threadIdx.x], ls[threadIdx.x]);
    else if (threadIdx.x < 128) atomicAdd(&ssq[threadIdx.x - 64], ls[threadIdx.x]);
}

// ---------------- final: out = relu(BN2(h2)) @ Wf + bf ----------------
__global__ __launch_bounds__(256) void final_k(const float* __restrict__ h,
                                               const float* __restrict__ coef,
                                               const float* __restrict__ Wf,
                                               const float* __restrict__ bf,
                                               float* __restrict__ out) {
    int wid = (blockIdx.x * 256 + threadIdx.x) >> 6;
    int lane = threadIdx.x & 63;
    if (wid >= NN) return;
    float v = fmaxf(fmaf(h[(size_t)wid * 64 + lane], coef[lane], coef[64 + lane]), 0.f)
              * Wf[lane];
    #pragma unroll
    for (int o = 32; o > 0; o >>= 1) v += __shfl_down(v, o);
    if (lane == 0) out[wid] = v + bf[0];
}

extern "C" void kernel_launch(void* const* d_in, const int* in_sizes, int n_in,
                              void* d_out, int out_size, void* d_ws, size_t ws_size,
                              hipStream_t stream) {
    const float* x   = (const float*)d_in[0];
    const int*   ei  = (const int*)d_in[1];
    const int*   src = ei;
    const int*   dst = ei + NE;
    const float* W1  = (const float*)d_in[2];
    const float* b1  = (const float*)d_in[3];
    const float* g1  = (const float*)d_in[4];
    const float* be1 = (const float*)d_in[5];
    const float* W2  = (const float*)d_in[6];
    const float* b2  = (const float*)d_in[7];
    const float* g2  = (const float*)d_in[8];
    const float* be2 = (const float*)d_in[9];
    const float* Wf  = (const float*)d_in[10];
    const float* bf  = (const float*)d_in[11];
    float* out = (float*)d_out;

    // ---- workspace layout ----
    uint32* xwb   = (uint32*)d_ws;                     // NN*64 u32 (bf16 xw, both layers)
    uint32* agg1b = xwb + (size_t)NN * 64;             // NN*64 u32 (bf16 h1 pre-BN)
    float*  agg2  = (float*)(agg1b + (size_t)NN * 64); // NN*64 f32
    float*  dis   = agg2 + (size_t)NN * D2;            // NN
    float*  sums1 = dis + NN;                          // 128
    float*  ssq1  = sums1 + D1;
    float*  sums2 = ssq1 + D1;
    float*  ssq2  = sums2 + D2;
    float*  coef1 = ssq2 + D2;                         // 256
    float*  coef2 = coef1 + 2 * D1;                    // 128
    ushort* wt1   = (ushort*)(coef2 + 2 * D2);         // 128*128 bf16
    ushort* wt2   = wt1 + 128 * 128;                   // 64*128 bf16
    int*    cnt    = (int*)(wt2 + 64 * 128);           // NN
    int*    cur    = cnt + NN;                         // NN
    int*    rowptr = cur + NN;                         // NN+1
    int*    bsum   = rowptr + NN + 1;                  // 256
    int*    esrc   = bsum + 256;                       // NE
    float*  ew     = (float*)(esrc + NE);              // NE

    hipMemsetAsync(cnt, 0, sizeof(int) * 2 * NN, stream);
    hipMemsetAsync(sums1, 0, sizeof(float) * (2 * D1 + 2 * D2), stream);

    // ---- CSR build + weight prep ----
    cnt_k<<<(NE + 255) / 256, 256, 0, stream>>>(dst, cnt);
    make_dis_k<<<(NN + 255) / 256, 256, 0, stream>>>(cnt, dis);
    scan1_k<<<NB_SCAN, SCAN_CHUNK, 0, stream>>>(cnt, rowptr, bsum);
    scan2_k<<<1, 64, 0, stream>>>(bsum);
    scan3_k<<<(NN + 255) / 256, 256, 0, stream>>>(rowptr, bsum);
    fill_k<<<(NE + 255) / 256, 256, 0, stream>>>(src, dst, rowptr, dis, cur, esrc, ew);
    wt_k<<<(128 * 128 + 64 * 128 + 255) / 256, 256, 0, stream>>>(W1, W2, wt1, wt2);

    // ---- layer 1 ----
    mgemm_k<128, false><<<(NN + 63) / 64, 256, 0, stream>>>(x, wt1, nullptr, (ushort*)xwb);
    agg128_k<<<2048, 256, 0, stream>>>(rowptr, esrc, ew, dis, xwb, b1, agg1b, sums1, ssq1);
    bncoef_k<<<1, 128, 0, stream>>>(sums1, ssq1, g1, be1, coef1, D1);

    // ---- layer 2 (BN1+ReLU fused into GEMM input load, bf16 input) ----
    mgemm_k<64, true><<<(NN + 63) / 64, 256, 0, stream>>>(agg1b, wt2, coef1, (ushort*)xwb);
    agg64_k<<<2048, 256, 0, stream>>>(rowptr, esrc, ew, dis, xwb, b2, agg2, sums2, ssq2);
    bncoef_k<<<1, 64, 0, stream>>>(sums2, ssq2, g2, be2, coef2, D2);

    // ---- final projection (BN2+ReLU fused) ----
    final_k<<<(NN * 64 + 255) / 256, 256, 0, stream>>>(agg2, coef2, Wf, bf, out);
}